// Round 9
// baseline (443.704 us; speedup 1.0000x reference)
//
#include <hip/hip_runtime.h>
#include <hip/hip_bf16.h>
#include <cstdint>
#include <cstddef>

#define B_N 4096
typedef short short8 __attribute__((ext_vector_type(8)));
typedef float f32x4 __attribute__((ext_vector_type(4)));
typedef float f32x2 __attribute__((ext_vector_type(2)));

// ws layout (float units)
static constexpr size_t H2B_OFF    = 0;                                  // 4096*4096 ushort
static constexpr size_t POOLED_OFF = 8388608;
static constexpr size_t EIDX_OFF   = POOLED_OFF + (size_t)B_N * 16;
static constexpr size_t EW_OFF     = EIDX_OFF + B_N;                     // B f
static constexpr size_t ORDER_OFF  = EW_OFF + B_N;                       // 4*B int
static constexpr size_t CNT_OFF    = ORDER_OFF + (size_t)4 * B_N;        // counts[4] + sync[ticket,gate] (legacy psum slots)
static constexpr size_t PSUM_OFF   = CNT_OFF + 4;
static constexpr size_t W2R_OFF    = PSUM_OFF + 4;                       // 73728 ushort
static constexpr size_t W1R_OFF    = W2R_OFF + 36864;                    // 2097152 ushort
static constexpr size_t W1C_OFF    = W1R_OFF + 1048576;                  // 4096 ushort

__device__ __forceinline__ unsigned int f2bf(float f) {
  unsigned int u = __float_as_uint(f);
  return (u + 0x7fffu + ((u >> 16) & 1u)) >> 16;   // RNE bf16
}
__device__ __forceinline__ unsigned int pkbf(float lo, float hi) {
  float2 f; f.x = lo; f.y = hi;
  __hip_bfloat162 b = __float22bfloat162_rn(f);     // v_cvt_pk_bf16_f32
  union { __hip_bfloat162 b; unsigned u; } c; c.b = b; return c.u;
}

// ---- conv1 A-fragment gather from ic-interleaved fp32 image (packed bf16 cvt) ----
__device__ __forceinline__ short8 gather_a(const float* __restrict__ base,
                                           const int* goff, bool isq1, bool isq3) {
  const float a0 = base[goff[0]];
  float       a1 = base[goff[0] + 1];
  const float b0 = base[goff[1]], b1 = base[goff[1] + 1];
  const float c0 = base[goff[2]], c1 = base[goff[2] + 1];
  const float d0 = base[goff[3]], d1 = base[goff[3] + 1];
  a1 = isq1 ? base[102] : a1;          // patch: p=9 (row 1, c 0) for q==1 lanes
  union { unsigned u[4]; short8 s; } r;
  r.u[0] = pkbf(a0, a1);
  r.u[1] = pkbf(b0, isq3 ? 0.f : b1);  // p>=27 zero padding (q==3)
  r.u[2] = isq3 ? 0u : pkbf(c0, c1);
  r.u[3] = isq3 ? 0u : pkbf(d0, d1);
  return r.s;
}

// ---------------- K1: ticket-repack + FUSED router + conv1 MFMA + conv2 MFMA ----------------
// Launch-count reduction (R8 lesson): the cooperative gg.sync() corrupted under graph
// capture. This version needs NO grid barrier: repack jobs are work-stolen via a global
// ticket (gating jobs w2r/w1c first, then w1r), each gating job releases with
// __threadfence + atomicAdd(gate); blocks spin on gate==304 (device-scope atomics,
// coherent point) AFTER stage+router, then acquire-fence before reading w1c/w2r.
// Ticket holders are resident by construction -> deadlock impossible regardless of
// dispatch order/residency. w1r is consumed by K4 across the kernel boundary (ordered).
// All router/conv arithmetic verbatim R7 -> bit-identical outputs.
__global__ __launch_bounds__(256, 3) void k_experts_conv(const float* __restrict__ x,
    const float* __restrict__ gw, const float* __restrict__ gb,
    const float* __restrict__ gwfc, const float* __restrict__ gbfc,
    const float* __restrict__ wc1, const float* __restrict__ b1g,
    const float* __restrict__ wc2, const float* __restrict__ b2g,
    const float* __restrict__ wfc1,
    unsigned short* __restrict__ w1c, unsigned short* __restrict__ w2r,
    unsigned short* __restrict__ w1r,
    unsigned short* __restrict__ h2b, float* __restrict__ probs_out,
    float* __restrict__ ewt, int* __restrict__ counts, int* __restrict__ order) {
  __shared__ __align__(16) float xpi[3572];                  // 14288 B
  __shared__ __align__(16) unsigned short h1s[18 * 18 * 36]; // 23328 B
  __shared__ float red[16 * 33];                             // 2112 B
  __shared__ float pooled_s[16];
  __shared__ int es;
  __shared__ int jslot;
  const int b = blockIdx.x, t = threadIdx.x;
  int* const ticket = counts + 4;    // legacy psum slot 0 (memset to 0 each launch)
  int* const gate   = counts + 5;    // legacy psum slot 1
  // ---- work-stealing repack: 0..287 w2r, 288..303 w1c (gating), 304..2351 w1r ----
  for (;;) {
    if (t == 0) jslot = atomicAdd(ticket, 1);
    __syncthreads();
    const int j = jslot;
    if (j >= 2352) break;
    if (j < 288) {                    // w2r: [e][s][oc][ic] bf16
      const int i = j * 256 + t;
      const int ic = i & 31, jj = i >> 5;
      const int oc = jj & 63, j2 = jj >> 6;
      const int s = j2 % 9, e = j2 / 9;
      w2r[i] = (unsigned short)f2bf(wc2[(((size_t)e * 64 + oc) * 32 + ic) * 9 + s]);
    } else if (j < 304) {             // w1c: conv1 K=27(+pad) fragments
      const int i = (j - 288) * 256 + t;
      const int jx = i & 7, n16r = (i >> 3) & 15, qr = (i >> 7) & 3, nt = (i >> 9) & 1, e = i >> 10;
      const int k = qr * 8 + jx;
      float v = 0.f;
      if (k < 27) {
        const int ky = k / 9, c = k % 9, kx = c / 3, ic = c % 3;
        v = wc1[((e * 32 + nt * 16 + n16r) * 3 + ic) * 9 + ky * 3 + kx];
      }
      w1c[i] = (unsigned short)f2bf(v);
    } else {                          // w1r: elementwise fp32 -> bf16 (no flag; next-kernel consumer)
      const int i = (j - 304) * 256 + t;
      const float4 v = ((const float4*)wfc1)[i];
      ushort4 u;
      u.x = (unsigned short)f2bf(v.x); u.y = (unsigned short)f2bf(v.y);
      u.z = (unsigned short)f2bf(v.z); u.w = (unsigned short)f2bf(v.w);
      *(ushort4*)(w1r + 4 * (size_t)i) = u;
    }
    __syncthreads();                  // drain block stores (vmcnt) before release
    if (t == 0 && j < 304) { __threadfence(); atomicAdd(gate, 1); }
  }
  // ---- stage sample image ----
  {
    uint4 z4 = make_uint4(0, 0, 0, 0);
    uint4* z1 = (uint4*)h1s;
    for (int i = t; i < 1458; i += 256) z1[i] = z4;
    uint4* z2 = (uint4*)xpi;
    for (int i = t; i < 893; i += 256) z2[i] = z4;
  }
  __syncthreads();
  const float4* x4 = (const float4*)(x + (size_t)b * 3072);
  for (int i = t; i < 768; i += 256) {
    float4 v = x4[i];
    int flat = i * 4, ic = flat >> 10, rem = flat & 1023, row = rem >> 5, col = rem & 31;
    float* d = &xpi[(row + 1) * 102 + (col + 1) * 3 + ic];
    d[0] = v.x; d[3] = v.y; d[6] = v.z; d[9] = v.w;
  }
  __syncthreads();
  // ---- fused router (packed fp32, bit-identical to scalar path) ----
  {
    const int ty = t >> 4, tx = t & 15;
    f32x2 wp[3][4][3];
#pragma unroll
    for (int ic = 0; ic < 3; ++ic)
#pragma unroll
    for (int rr = 0; rr < 4; ++rr) {
      const float* p = &xpi[(2 * ty + rr) * 102 + (2 * tx) * 3 + ic];
      const float r0 = p[0], r1 = p[3], r2 = p[6], r3 = p[9];
      wp[ic][rr][0] = (f32x2){r0, r1};
      wp[ic][rr][1] = (f32x2){r1, r2};
      wp[ic][rr][2] = (f32x2){r2, r3};
    }
    float sums[16];
#pragma unroll
    for (int oc = 0; oc < 16; ++oc) {
      const float bias = gb[oc];
      f32x2 A0 = {bias, bias};   // (a00, a01)
      f32x2 A1 = {bias, bias};   // (a10, a11)
#pragma unroll
      for (int ic = 0; ic < 3; ++ic)
#pragma unroll
      for (int ky = 0; ky < 3; ++ky)
#pragma unroll
      for (int kx = 0; kx < 3; ++kx) {
        const float wv2 = gw[oc * 27 + ic * 9 + ky * 3 + kx];
        const f32x2 ws = {wv2, wv2};
        A0 = __builtin_elementwise_fma(wp[ic][ky][kx], ws, A0);      // v_pk_fma_f32
        A1 = __builtin_elementwise_fma(wp[ic][ky + 1][kx], ws, A1);
      }
      sums[oc] = fmaxf(A0.x, 0.f) + fmaxf(A0.y, 0.f) + fmaxf(A1.x, 0.f) + fmaxf(A1.y, 0.f);
    }
    const int rl = t & 63, wid = t >> 6;
#pragma unroll
    for (int oc = 0; oc < 16; ++oc) {
      float s = sums[oc];
      s += __shfl_xor(s, 1);
      s += __shfl_xor(s, 2);
      s += __shfl_xor(s, 4);
      sums[oc] = s;
    }
    if ((rl & 7) == 0) {
      const int slot = wid * 8 + (rl >> 3);
#pragma unroll
      for (int oc = 0; oc < 16; ++oc) red[oc * 33 + slot] = sums[oc];
    }
    __syncthreads();
    if (t < 16) {
      float s = 0.f;
#pragma unroll
      for (int i = 0; i < 32; ++i) s += red[t * 33 + i];
      pooled_s[t] = s * (1.f / 1024.f);
    }
    __syncthreads();
    if (t == 0) {   // verbatim per-sample router FC + softmax + top1
      float l[4];
#pragma unroll
      for (int j = 0; j < 4; ++j) {
        float s = gbfc[j];
#pragma unroll
        for (int i = 0; i < 16; ++i) s += pooled_s[i] * gwfc[j * 16 + i];
        l[j] = s;
      }
      const float mx = fmaxf(fmaxf(l[0], l[1]), fmaxf(l[2], l[3]));
      float ex[4], ssum = 0.f;
#pragma unroll
      for (int j = 0; j < 4; ++j) { ex[j] = expf(l[j] - mx); ssum += ex[j]; }
      const float inv = 1.f / ssum;
      float p[4];
#pragma unroll
      for (int j = 0; j < 4; ++j) p[j] = ex[j] * inv;
      *(float4*)(probs_out + (size_t)b * 4) = make_float4(p[0], p[1], p[2], p[3]);
      int em = 0; float pm = p[0];
#pragma unroll
      for (int j = 1; j < 4; ++j) if (p[j] > pm) { pm = p[j]; em = j; }
      ewt[b] = pm;
      const int slot = atomicAdd(&counts[em], 1);
      order[em * B_N + slot] = b;
      es = em;
    }
    __syncthreads();
  }
  // ---- gate: all 304 w1c/w2r jobs complete, then acquire before weight reads ----
  if (t == 0) {
    while (atomicAdd(gate, 0) < 304) __builtin_amdgcn_s_sleep(2);
    __threadfence();
  }
  __syncthreads();
  const int e = __builtin_amdgcn_readfirstlane(es);
  const int lane = t & 63, wv = t >> 6;
  const int n16 = lane & 15, q = lane >> 4;
  // ---- conv1: MFMA 16x16x32, K=27(+pad) ----
  {
    const bool isq1 = (q == 1), isq3 = (q == 3);
    const short8 wb0 = *(const short8*)(w1c + (((e * 2 + 0) * 4 + q) * 16 + n16) * 8);
    const short8 wb1 = *(const short8*)(w1c + (((e * 2 + 1) * 4 + q) * 16 + n16) * 8);
    const float bias0 = b1g[e * 32 + n16];
    const float bias1 = b1g[e * 32 + 16 + n16];
    int goff[4];
#pragma unroll
    for (int t4 = 0; t4 < 4; ++t4) {
      const int p0 = q * 8 + 2 * t4;
      const int r = (p0 * 939) >> 13;        // p0/9 for p0<32
      goff[t4] = r * 102 + (p0 - 9 * r);
    }
    for (int pid = 0; pid < 8; ++pid) {
      const int pairid = wv * 8 + pid;
      const int yp = pairid >> 1, xh = pairid & 1;
      const float* baseA = &xpi[(2 * yp) * 102 + (xh * 16 + n16) * 3];
      const short8 afA = gather_a(baseA, goff, isq1, isq3);
      const short8 afB = gather_a(baseA + 102, goff, isq1, isq3);
      f32x4 aA0 = {bias0, bias0, bias0, bias0}, aA1 = {bias1, bias1, bias1, bias1};
      f32x4 aB0 = aA0, aB1 = aA1;
      aA0 = __builtin_amdgcn_mfma_f32_16x16x32_bf16(afA, wb0, aA0, 0, 0, 0);
      aA1 = __builtin_amdgcn_mfma_f32_16x16x32_bf16(afA, wb1, aA1, 0, 0, 0);
      aB0 = __builtin_amdgcn_mfma_f32_16x16x32_bf16(afB, wb0, aB0, 0, 0, 0);
      aB1 = __builtin_amdgcn_mfma_f32_16x16x32_bf16(afB, wb1, aB1, 0, 0, 0);
      const int px = xh * 8 + 2 * q;
      unsigned short* hw = &h1s[((yp + 1) * 18 + (px + 1)) * 36];
      const float p00 = fmaxf(fmaxf(fmaxf(aA0[0], aA0[1]), fmaxf(aB0[0], aB0[1])), 0.f);
      const float p01 = fmaxf(fmaxf(fmaxf(aA0[2], aA0[3]), fmaxf(aB0[2], aB0[3])), 0.f);
      const float p10 = fmaxf(fmaxf(fmaxf(aA1[0], aA1[1]), fmaxf(aB1[0], aB1[1])), 0.f);
      const float p11 = fmaxf(fmaxf(fmaxf(aA1[2], aA1[3]), fmaxf(aB1[2], aB1[3])), 0.f);
      hw[n16]           = (unsigned short)f2bf(p00);
      hw[16 + n16]      = (unsigned short)f2bf(p10);
      hw[36 + n16]      = (unsigned short)f2bf(p01);
      hw[36 + 16 + n16] = (unsigned short)f2bf(p11);
    }
  }
  __syncthreads();
  // ---- conv2: wave = 4 rows x all 64 oc; B streamed from global (L2) with prefetch ----
  {
    const unsigned short* wbase = w2r + (size_t)e * 18432 + n16 * 32 + q * 8;
    float bz[4];
#pragma unroll
    for (int nt = 0; nt < 4; ++nt) bz[nt] = b2g[e * 64 + nt * 16 + n16];
    f32x4 acc[4][4];
#pragma unroll
    for (int mt4 = 0; mt4 < 4; ++mt4)
#pragma unroll
      for (int nt = 0; nt < 4; ++nt) {
        acc[mt4][nt][0] = bz[nt]; acc[mt4][nt][1] = bz[nt];
        acc[mt4][nt][2] = bz[nt]; acc[mt4][nt][3] = bz[nt];
      }
    short8 Bc[4];
#pragma unroll
    for (int nt = 0; nt < 4; ++nt) Bc[nt] = *(const short8*)(wbase + nt * 512);
#pragma unroll
    for (int s = 0; s < 9; ++s) {
      const int ky = s / 3, kx = s % 3;
      short8 Bn[4];
      if (s < 8) {
#pragma unroll
        for (int nt = 0; nt < 4; ++nt)
          Bn[nt] = *(const short8*)(wbase + (s + 1) * 2048 + nt * 512);
      }
#pragma unroll
      for (int mt4 = 0; mt4 < 4; ++mt4) {
        const int mt = wv * 4 + mt4;
        const short8 af = *(const short8*)&h1s[((mt + ky) * 18 + n16 + kx) * 36 + q * 8];
#pragma unroll
        for (int nt = 0; nt < 4; ++nt)
          acc[mt4][nt] = __builtin_amdgcn_mfma_f32_16x16x32_bf16(af, Bc[nt], acc[mt4][nt], 0, 0, 0);
      }
      if (s < 8) {
#pragma unroll
        for (int nt = 0; nt < 4; ++nt) Bc[nt] = Bn[nt];
      }
    }
    __syncthreads();                        // all MFMA reads of h1s done
    float* h2s = (float*)h1s;               // [oc][68]
#pragma unroll
    for (int u2 = 0; u2 < 2; ++u2) {
      const int py = wv * 2 + u2;
#pragma unroll
      for (int nt = 0; nt < 4; ++nt) {
        const f32x4 a = acc[2 * u2][nt], c = acc[2 * u2 + 1][nt];
        float2 pv;
        pv.x = fmaxf(fmaxf(fmaxf(a[0], a[1]), fmaxf(c[0], c[1])), 0.f);
        pv.y = fmaxf(fmaxf(fmaxf(a[2], a[3]), fmaxf(c[2], c[3])), 0.f);
        *(float2*)&h2s[(nt * 16 + n16) * 68 + py * 8 + 2 * q] = pv;
      }
    }
  }
  __syncthreads();
  {
    const float* h2s = (const float*)h1s;
    unsigned short* dst = h2b + (size_t)b * 4096;
#pragma unroll
    for (int j = 0; j < 2; ++j) {
      const int f = 8 * (t + 256 * j);          // flat k = oc*64+py*8+px
      const float* src = &h2s[(f >> 6) * 68 + (f & 63)];
      float4 v0 = *(const float4*)src;
      float4 v1 = *(const float4*)(src + 4);
      unsigned int p0 = pkbf(v0.x, v0.y);
      unsigned int p1 = pkbf(v0.z, v0.w);
      unsigned int p2 = pkbf(v1.x, v1.y);
      unsigned int p3 = pkbf(v1.z, v1.w);
      *(uint4*)(dst + f) = make_uint4(p0, p1, p2, p3);
    }
  }
}

// ---------------- K4: bucketed fc1 (M=16, bf16 MFMA, reg-prefetch) + relu + fc2 fp32
// + aux (deterministic reduce of probs_out) ---------------- (verbatim R7)
__global__ __launch_bounds__(256) void k_fc(const unsigned short* __restrict__ h2b,
    const unsigned short* __restrict__ w1r, const float* __restrict__ b1g,
    const float* __restrict__ w2g, const float* __restrict__ b2g,
    const int* __restrict__ counts, const int* __restrict__ order,
    const float* __restrict__ ew, float* __restrict__ outp) {
  const int bid = blockIdx.x;
  const int t = threadIdx.x;
  if (bid == 0) {                            // aux loss (before any early-exit)
    const float* pr = outp + 40960;          // probs_out
    float s0 = 0.f, s1 = 0.f, s2 = 0.f, s3 = 0.f;
    for (int i = t; i < 4096; i += 256) {
      const float4 v = *(const float4*)(pr + (size_t)i * 4);
      s0 += v.x; s1 += v.y; s2 += v.z; s3 += v.w;
    }
#pragma unroll
    for (int k = 1; k < 64; k <<= 1) {
      s0 += __shfl_xor(s0, k); s1 += __shfl_xor(s1, k);
      s2 += __shfl_xor(s2, k); s3 += __shfl_xor(s3, k);
    }
    __shared__ float ax[4][4];
    if ((t & 63) == 0) {
      const int w = t >> 6;
      ax[w][0] = s0; ax[w][1] = s1; ax[w][2] = s2; ax[w][3] = s3;
    }
    __syncthreads();
    if (t == 0) {
      float a = 0.f;
#pragma unroll
      for (int j = 0; j < 4; ++j) {
        const float mp = (ax[0][j] + ax[1][j] + ax[2][j] + ax[3][j]) * (1.f / 4096.f) - 0.25f;
        a += mp * mp;
      }
      outp[57344] = a * 0.25f;
    }
  }
  const int e = bid >> 8, tile = bid & 255;
  const int n = counts[e];
  const int base = tile * 16;
  if (base >= n) return;
  __shared__ int sb[16];
  __shared__ float wgt[16];
  __shared__ __align__(16) unsigned short As[16][280];   // 16 x 256 k, stride 280 (bank-clean)
  __shared__ float f1s[16 * 132];
  if (t < 16) {
    const int idx = base + t;
    const int s = order[e * B_N + ((idx < n) ? idx : base)];
    sb[t] = s; wgt[t] = ew[s];
  }
  __syncthreads();
  const int lane = t & 63, wv = t >> 6;
  const int n16 = lane & 15, q = lane >> 4;
  const int oc0 = wv * 32 + n16;           // n-tile 2*wv
  const int oc1 = wv * 32 + 16 + n16;      // n-tile 2*wv+1
  const unsigned short* wb0 = w1r + ((size_t)(e * 128 + oc0)) * 4096 + q * 8;
  const unsigned short* wb1 = w1r + ((size_t)(e * 128 + oc1)) * 4096 + q * 8;
  f32x4 acc0 = {0.f, 0.f, 0.f, 0.f}, acc1 = {0.f, 0.f, 0.f, 0.f};
  const int ldrow = t >> 4, ldseg = t & 15;
  const unsigned short* asrc = h2b + (size_t)sb[ldrow] * 4096;
  uint4 r0 = *(const uint4*)(asrc + ldseg * 8);            // prefetch kc=0
  uint4 r1 = *(const uint4*)(asrc + (ldseg + 16) * 8);
  for (int kc = 0; kc < 4096; kc += 256) {
    *(uint4*)&As[ldrow][ldseg * 8] = r0;
    *(uint4*)&As[ldrow][(ldseg + 16) * 8] = r1;
    __syncthreads();
    if (kc + 256 < 4096) {                                 // prefetch next chunk (overlaps MFMA)
      r0 = *(const uint4*)(asrc + (kc + 256) + ldseg * 8);
      r1 = *(const uint4*)(asrc + (kc + 256) + (ldseg + 16) * 8);
    }
#pragma unroll
    for (int ks = 0; ks < 8; ++ks) {
      const short8 af = *(const short8*)&As[n16][ks * 32 + q * 8];   // A[m=n16][k]
      const short8 bf0 = *(const short8*)(wb0 + kc + ks * 32);       // B[k][n=oc0]
      const short8 bf1 = *(const short8*)(wb1 + kc + ks * 32);
      acc0 = __builtin_amdgcn_mfma_f32_16x16x32_bf16(af, bf0, acc0, 0, 0, 0);
      acc1 = __builtin_amdgcn_mfma_f32_16x16x32_bf16(af, bf1, acc1, 0, 0, 0);
    }
    __syncthreads();
  }
  // C layout: row m = q*4+r (sample), col = n16 (oc)
  const float* b1 = b1g + e * 128;
  const float bb0 = b1[oc0], bb1 = b1[oc1];
#pragma unroll
  for (int r = 0; r < 4; ++r) {
    const int m = q * 4 + r;
    f1s[m * 132 + oc0] = fmaxf(acc0[r] + bb0, 0.f);
    f1s[m * 132 + oc1] = fmaxf(acc1[r] + bb1, 0.f);
  }
  __syncthreads();
  int m = n - base; if (m > 16) m = 16;
  if (t < 160) {
    const int r = t / 10, o = t - r * 10;
    if (r < m) {
      const float* w2 = w2g + (e * 10 + o) * 128;
      float s = b2g[e * 10 + o];
#pragma unroll 8
      for (int c = 0; c < 128; ++c) s += f1s[r * 132 + c] * w2[c];
      outp[(size_t)sb[r] * 10 + o] = s * wgt[r];
    }
  }
}

extern "C" void kernel_launch(void* const* d_in, const int* in_sizes, int n_in,
                              void* d_out, int out_size, void* d_ws, size_t ws_size,
                              hipStream_t stream) {
  const float* x        = (const float*)d_in[0];
  const float* gw_conv  = (const float*)d_in[1];
  const float* gb_conv  = (const float*)d_in[2];
  const float* gw_fc    = (const float*)d_in[3];
  const float* gb_fc    = (const float*)d_in[4];
  const float* ew_conv1 = (const float*)d_in[5];
  const float* eb_conv1 = (const float*)d_in[6];
  const float* ew_conv2 = (const float*)d_in[7];
  const float* eb_conv2 = (const float*)d_in[8];
  const float* ew_fc1   = (const float*)d_in[9];
  const float* eb_fc1   = (const float*)d_in[10];
  const float* ew_fc2   = (const float*)d_in[11];
  const float* eb_fc2   = (const float*)d_in[12];
  float* out = (float*)d_out;
  float* ws  = (float*)d_ws;

  unsigned short* h2b = (unsigned short*)(ws + H2B_OFF);
  float* ew     = ws + EW_OFF;
  int*   order  = (int*)(ws + ORDER_OFF);
  int*   counts = (int*)(ws + CNT_OFF);
  unsigned short* w2r = (unsigned short*)(ws + W2R_OFF);
  unsigned short* w1r = (unsigned short*)(ws + W1R_OFF);
  unsigned short* w1c = (unsigned short*)(ws + W1C_OFF);

  // zero counts[4] + ticket + gate (24 B), stream-ordered (graph-capturable)
  hipMemsetAsync((void*)counts, 0, 24, stream);
  k_experts_conv<<<4096, 256, 0, stream>>>(x, gw_conv, gb_conv, gw_fc, gb_fc,
                                           ew_conv1, eb_conv1, ew_conv2, eb_conv2,
                                           ew_fc1, w1c, w2r, w1r, h2b,
                                           out + 40960, ew, counts, order);
  k_fc<<<1024, 256, 0, stream>>>(h2b, w1r, eb_fc1, ew_fc2, eb_fc2,
                                 counts, order, ew, out);
}

// Round 10
// 244.849 us; speedup vs baseline: 1.8122x; 1.8122x over previous
//
#include <hip/hip_runtime.h>
#include <hip/hip_bf16.h>
#include <cstdint>
#include <cstddef>

#define B_N 4096
typedef short short8 __attribute__((ext_vector_type(8)));
typedef float f32x4 __attribute__((ext_vector_type(4)));
typedef float f32x2 __attribute__((ext_vector_type(2)));

// ws layout (float units)
static constexpr size_t H2B_OFF    = 0;                                  // 4096*4096 ushort
static constexpr size_t POOLED_OFF = 8388608;
static constexpr size_t EIDX_OFF   = POOLED_OFF + (size_t)B_N * 16;
static constexpr size_t EW_OFF     = EIDX_OFF + B_N;                     // B f
static constexpr size_t ORDER_OFF  = EW_OFF + B_N;                       // 4*B int
static constexpr size_t CNT_OFF    = ORDER_OFF + (size_t)4 * B_N;        // 4 int
static constexpr size_t PSUM_OFF   = CNT_OFF + 4;
static constexpr size_t W2R_OFF    = PSUM_OFF + 4;                       // 73728 ushort
static constexpr size_t W1R_OFF    = W2R_OFF + 36864;                    // 2097152 ushort
static constexpr size_t W1C_OFF    = W1R_OFF + 1048576;                  // 4096 ushort

__device__ __forceinline__ unsigned int f2bf(float f) {
  unsigned int u = __float_as_uint(f);
  return (u + 0x7fffu + ((u >> 16) & 1u)) >> 16;   // RNE bf16
}
__device__ __forceinline__ unsigned int pkbf(float lo, float hi) {
  float2 f; f.x = lo; f.y = hi;
  __hip_bfloat162 b = __float22bfloat162_rn(f);     // v_cvt_pk_bf16_f32
  union { __hip_bfloat162 b; unsigned u; } c; c.b = b; return c.u;
}

// ---------------- K1: weight repacks ONLY (router fused into K3) ----------------
// (R9 lesson: merging this into K3 via ticket+spin-gate collapsed — same-address
// atomic RMW polling from ~768 resident blocks saturates the L2 atomic pipe
// (conv 126->335 us, all pipes idle). Node count, not kernel count, drives the
// ~65 us residue (memset node == kernel node). Keep the clean 3-kernel pipeline.)
__global__ __launch_bounds__(256) void k_front(
    const float* __restrict__ wfc1, unsigned short* __restrict__ w1r,
    const float* __restrict__ wc2, unsigned short* __restrict__ w2r,
    const float* __restrict__ wc1, unsigned short* __restrict__ w1c,
    int* __restrict__ counts) {
  const int rb = blockIdx.x, t = threadIdx.x;
  if (rb < 2048) {
    const int i = rb * 256 + t;                    // float4 index
    const float4 v = ((const float4*)wfc1)[i];
    ushort4 u;
    u.x = (unsigned short)f2bf(v.x); u.y = (unsigned short)f2bf(v.y);
    u.z = (unsigned short)f2bf(v.z); u.w = (unsigned short)f2bf(v.w);
    *(ushort4*)(w1r + 4 * (size_t)i) = u;
  } else if (rb < 2336) {
    if (rb == 2048 && t < 8) counts[t] = 0;        // counts[4] (+legacy psum[4])
    const int i = (rb - 2048) * 256 + t;
    if (i < 4 * 9 * 64 * 32) {
      const int ic = i & 31, j = i >> 5;
      const int oc = j & 63, j2 = j >> 6;
      const int s = j2 % 9, e = j2 / 9;
      w2r[i] = (unsigned short)f2bf(wc2[(((size_t)e * 64 + oc) * 32 + ic) * 9 + s]);
    }
  } else {
    const int i = (rb - 2336) * 256 + t;           // [0, 4096)
    if (i < 4096) {
      const int j = i & 7, n16 = (i >> 3) & 15, q = (i >> 7) & 3, nt = (i >> 9) & 1, e = i >> 10;
      const int k = q * 8 + j;
      float v = 0.f;
      if (k < 27) {
        const int ky = k / 9, c = k % 9, kx = c / 3, ic = c % 3;
        v = wc1[((e * 32 + nt * 16 + n16) * 3 + ic) * 9 + ky * 3 + kx];
      }
      w1c[i] = (unsigned short)f2bf(v);
    }
  }
}

// ---- conv1 A-fragment gather from ic-interleaved fp32 image (packed bf16 cvt) ----
__device__ __forceinline__ short8 gather_a(const float* __restrict__ base,
                                           const int* goff, bool isq1, bool isq3) {
  const float a0 = base[goff[0]];
  float       a1 = base[goff[0] + 1];
  const float b0 = base[goff[1]], b1 = base[goff[1] + 1];
  const float c0 = base[goff[2]], c1 = base[goff[2] + 1];
  const float d0 = base[goff[3]], d1 = base[goff[3] + 1];
  a1 = isq1 ? base[102] : a1;          // patch: p=9 (row 1, c 0) for q==1 lanes
  union { unsigned u[4]; short8 s; } r;
  r.u[0] = pkbf(a0, a1);
  r.u[1] = pkbf(b0, isq3 ? 0.f : b1);  // p>=27 zero padding (q==3)
  r.u[2] = isq3 ? 0u : pkbf(c0, c1);
  r.u[3] = isq3 ? 0u : pkbf(d0, d1);
  return r.s;
}

// ---------------- K3: FUSED router (conv16+pool+fc+softmax+top1, packed fp32)
// + conv1 MFMA -> h1 bf16 LDS -> conv2 MFMA -> h2 bf16 (verbatim R7) ----------------
__global__ __launch_bounds__(256, 3) void k_experts_conv(const float* __restrict__ x,
    const float* __restrict__ gw, const float* __restrict__ gb,
    const float* __restrict__ gwfc, const float* __restrict__ gbfc,
    const unsigned short* __restrict__ w1c, const float* __restrict__ b1g,
    const unsigned short* __restrict__ w2r, const float* __restrict__ b2g,
    unsigned short* __restrict__ h2b, float* __restrict__ probs_out,
    float* __restrict__ ewt, int* __restrict__ counts, int* __restrict__ order) {
  __shared__ __align__(16) float xpi[3572];                  // 14288 B
  __shared__ __align__(16) unsigned short h1s[18 * 18 * 36]; // 23328 B
  __shared__ float red[16 * 33];                             // 2112 B
  __shared__ float pooled_s[16];
  __shared__ int es;
  const int b = blockIdx.x, t = threadIdx.x;
  {
    uint4 z4 = make_uint4(0, 0, 0, 0);
    uint4* z1 = (uint4*)h1s;
    for (int i = t; i < 1458; i += 256) z1[i] = z4;
    uint4* z2 = (uint4*)xpi;
    for (int i = t; i < 893; i += 256) z2[i] = z4;
  }
  __syncthreads();
  const float4* x4 = (const float4*)(x + (size_t)b * 3072);
  for (int i = t; i < 768; i += 256) {
    float4 v = x4[i];
    int flat = i * 4, ic = flat >> 10, rem = flat & 1023, row = rem >> 5, col = rem & 31;
    float* d = &xpi[(row + 1) * 102 + (col + 1) * 3 + ic];
    d[0] = v.x; d[3] = v.y; d[6] = v.z; d[9] = v.w;
  }
  __syncthreads();
  // ---- fused router (packed fp32): values bit-identical to the scalar path ----
  {
    const int ty = t >> 4, tx = t & 15;
    f32x2 wp[3][4][3];
#pragma unroll
    for (int ic = 0; ic < 3; ++ic)
#pragma unroll
    for (int rr = 0; rr < 4; ++rr) {
      const float* p = &xpi[(2 * ty + rr) * 102 + (2 * tx) * 3 + ic];
      const float r0 = p[0], r1 = p[3], r2 = p[6], r3 = p[9];
      wp[ic][rr][0] = (f32x2){r0, r1};
      wp[ic][rr][1] = (f32x2){r1, r2};
      wp[ic][rr][2] = (f32x2){r2, r3};
    }
    float sums[16];
#pragma unroll
    for (int oc = 0; oc < 16; ++oc) {
      const float bias = gb[oc];
      f32x2 A0 = {bias, bias};   // (a00, a01)
      f32x2 A1 = {bias, bias};   // (a10, a11)
#pragma unroll
      for (int ic = 0; ic < 3; ++ic)
#pragma unroll
      for (int ky = 0; ky < 3; ++ky)
#pragma unroll
      for (int kx = 0; kx < 3; ++kx) {
        const float wv2 = gw[oc * 27 + ic * 9 + ky * 3 + kx];
        const f32x2 ws = {wv2, wv2};
        A0 = __builtin_elementwise_fma(wp[ic][ky][kx], ws, A0);      // v_pk_fma_f32
        A1 = __builtin_elementwise_fma(wp[ic][ky + 1][kx], ws, A1);
      }
      sums[oc] = fmaxf(A0.x, 0.f) + fmaxf(A0.y, 0.f) + fmaxf(A1.x, 0.f) + fmaxf(A1.y, 0.f);
    }
    const int rl = t & 63, wid = t >> 6;
#pragma unroll
    for (int oc = 0; oc < 16; ++oc) {
      float s = sums[oc];
      s += __shfl_xor(s, 1);
      s += __shfl_xor(s, 2);
      s += __shfl_xor(s, 4);
      sums[oc] = s;
    }
    if ((rl & 7) == 0) {
      const int slot = wid * 8 + (rl >> 3);
#pragma unroll
      for (int oc = 0; oc < 16; ++oc) red[oc * 33 + slot] = sums[oc];
    }
    __syncthreads();
    if (t < 16) {
      float s = 0.f;
#pragma unroll
      for (int i = 0; i < 32; ++i) s += red[t * 33 + i];
      pooled_s[t] = s * (1.f / 1024.f);
    }
    __syncthreads();
    if (t == 0) {   // verbatim per-sample router FC + softmax + top1
      float l[4];
#pragma unroll
      for (int j = 0; j < 4; ++j) {
        float s = gbfc[j];
#pragma unroll
        for (int i = 0; i < 16; ++i) s += pooled_s[i] * gwfc[j * 16 + i];
        l[j] = s;
      }
      const float mx = fmaxf(fmaxf(l[0], l[1]), fmaxf(l[2], l[3]));
      float ex[4], ssum = 0.f;
#pragma unroll
      for (int j = 0; j < 4; ++j) { ex[j] = expf(l[j] - mx); ssum += ex[j]; }
      const float inv = 1.f / ssum;
      float p[4];
#pragma unroll
      for (int j = 0; j < 4; ++j) p[j] = ex[j] * inv;
      *(float4*)(probs_out + (size_t)b * 4) = make_float4(p[0], p[1], p[2], p[3]);
      int em = 0; float pm = p[0];
#pragma unroll
      for (int j = 1; j < 4; ++j) if (p[j] > pm) { pm = p[j]; em = j; }
      ewt[b] = pm;
      const int slot = atomicAdd(&counts[em], 1);
      order[em * B_N + slot] = b;
      es = em;
    }
    __syncthreads();
  }
  const int e = __builtin_amdgcn_readfirstlane(es);
  const int lane = t & 63, wv = t >> 6;
  const int n16 = lane & 15, q = lane >> 4;
  // ---- conv1: MFMA 16x16x32, K=27(+pad) ----
  {
    const bool isq1 = (q == 1), isq3 = (q == 3);
    const short8 wb0 = *(const short8*)(w1c + (((e * 2 + 0) * 4 + q) * 16 + n16) * 8);
    const short8 wb1 = *(const short8*)(w1c + (((e * 2 + 1) * 4 + q) * 16 + n16) * 8);
    const float bias0 = b1g[e * 32 + n16];
    const float bias1 = b1g[e * 32 + 16 + n16];
    int goff[4];
#pragma unroll
    for (int t4 = 0; t4 < 4; ++t4) {
      const int p0 = q * 8 + 2 * t4;
      const int r = (p0 * 939) >> 13;        // p0/9 for p0<32
      goff[t4] = r * 102 + (p0 - 9 * r);
    }
    for (int pid = 0; pid < 8; ++pid) {
      const int pairid = wv * 8 + pid;
      const int yp = pairid >> 1, xh = pairid & 1;
      const float* baseA = &xpi[(2 * yp) * 102 + (xh * 16 + n16) * 3];
      const short8 afA = gather_a(baseA, goff, isq1, isq3);
      const short8 afB = gather_a(baseA + 102, goff, isq1, isq3);
      f32x4 aA0 = {bias0, bias0, bias0, bias0}, aA1 = {bias1, bias1, bias1, bias1};
      f32x4 aB0 = aA0, aB1 = aA1;
      aA0 = __builtin_amdgcn_mfma_f32_16x16x32_bf16(afA, wb0, aA0, 0, 0, 0);
      aA1 = __builtin_amdgcn_mfma_f32_16x16x32_bf16(afA, wb1, aA1, 0, 0, 0);
      aB0 = __builtin_amdgcn_mfma_f32_16x16x32_bf16(afB, wb0, aB0, 0, 0, 0);
      aB1 = __builtin_amdgcn_mfma_f32_16x16x32_bf16(afB, wb1, aB1, 0, 0, 0);
      const int px = xh * 8 + 2 * q;
      unsigned short* hw = &h1s[((yp + 1) * 18 + (px + 1)) * 36];
      const float p00 = fmaxf(fmaxf(fmaxf(aA0[0], aA0[1]), fmaxf(aB0[0], aB0[1])), 0.f);
      const float p01 = fmaxf(fmaxf(fmaxf(aA0[2], aA0[3]), fmaxf(aB0[2], aB0[3])), 0.f);
      const float p10 = fmaxf(fmaxf(fmaxf(aA1[0], aA1[1]), fmaxf(aB1[0], aB1[1])), 0.f);
      const float p11 = fmaxf(fmaxf(fmaxf(aA1[2], aA1[3]), fmaxf(aB1[2], aB1[3])), 0.f);
      hw[n16]           = (unsigned short)f2bf(p00);
      hw[16 + n16]      = (unsigned short)f2bf(p10);
      hw[36 + n16]      = (unsigned short)f2bf(p01);
      hw[36 + 16 + n16] = (unsigned short)f2bf(p11);
    }
  }
  __syncthreads();
  // ---- conv2: wave = 4 rows x all 64 oc; B streamed from global (L2) with prefetch ----
  {
    const unsigned short* wbase = w2r + (size_t)e * 18432 + n16 * 32 + q * 8;
    float bz[4];
#pragma unroll
    for (int nt = 0; nt < 4; ++nt) bz[nt] = b2g[e * 64 + nt * 16 + n16];
    f32x4 acc[4][4];
#pragma unroll
    for (int mt4 = 0; mt4 < 4; ++mt4)
#pragma unroll
      for (int nt = 0; nt < 4; ++nt) {
        acc[mt4][nt][0] = bz[nt]; acc[mt4][nt][1] = bz[nt];
        acc[mt4][nt][2] = bz[nt]; acc[mt4][nt][3] = bz[nt];
      }
    short8 Bc[4];
#pragma unroll
    for (int nt = 0; nt < 4; ++nt) Bc[nt] = *(const short8*)(wbase + nt * 512);
#pragma unroll
    for (int s = 0; s < 9; ++s) {
      const int ky = s / 3, kx = s % 3;
      short8 Bn[4];
      if (s < 8) {
#pragma unroll
        for (int nt = 0; nt < 4; ++nt)
          Bn[nt] = *(const short8*)(wbase + (s + 1) * 2048 + nt * 512);
      }
#pragma unroll
      for (int mt4 = 0; mt4 < 4; ++mt4) {
        const int mt = wv * 4 + mt4;
        const short8 af = *(const short8*)&h1s[((mt + ky) * 18 + n16 + kx) * 36 + q * 8];
#pragma unroll
        for (int nt = 0; nt < 4; ++nt)
          acc[mt4][nt] = __builtin_amdgcn_mfma_f32_16x16x32_bf16(af, Bc[nt], acc[mt4][nt], 0, 0, 0);
      }
      if (s < 8) {
#pragma unroll
        for (int nt = 0; nt < 4; ++nt) Bc[nt] = Bn[nt];
      }
    }
    __syncthreads();                        // all MFMA reads of h1s done
    float* h2s = (float*)h1s;               // [oc][68]
#pragma unroll
    for (int u2 = 0; u2 < 2; ++u2) {
      const int py = wv * 2 + u2;
#pragma unroll
      for (int nt = 0; nt < 4; ++nt) {
        const f32x4 a = acc[2 * u2][nt], c = acc[2 * u2 + 1][nt];
        float2 pv;
        pv.x = fmaxf(fmaxf(fmaxf(a[0], a[1]), fmaxf(c[0], c[1])), 0.f);
        pv.y = fmaxf(fmaxf(fmaxf(a[2], a[3]), fmaxf(c[2], c[3])), 0.f);
        *(float2*)&h2s[(nt * 16 + n16) * 68 + py * 8 + 2 * q] = pv;
      }
    }
  }
  __syncthreads();
  {
    const float* h2s = (const float*)h1s;
    unsigned short* dst = h2b + (size_t)b * 4096;
#pragma unroll
    for (int j = 0; j < 2; ++j) {
      const int f = 8 * (t + 256 * j);          // flat k = oc*64+py*8+px
      const float* src = &h2s[(f >> 6) * 68 + (f & 63)];
      float4 v0 = *(const float4*)src;
      float4 v1 = *(const float4*)(src + 4);
      unsigned int p0 = pkbf(v0.x, v0.y);
      unsigned int p1 = pkbf(v0.z, v0.w);
      unsigned int p2 = pkbf(v1.x, v1.y);
      unsigned int p3 = pkbf(v1.z, v1.w);
      *(uint4*)(dst + f) = make_uint4(p0, p1, p2, p3);
    }
  }
}

// ---------------- K4: bucketed fc1, 512 threads / 8 waves (oc-split 16/wave) ----------------
// k_fc was latency-starved: ~260 active blocks on 256 CUs = 1 wave/SIMD, zero TLP,
// L2 weight-load latency fully exposed (45 us). 8 waves x 16 oc doubles waves/SIMD.
// Per-(sample,oc) MFMA chain identical (same kc/ks order, same fragments, acc=0 +
// bias at end) -> bit-identical. Aux-loss arithmetic kept verbatim (t<256 guard).
__global__ __launch_bounds__(512) void k_fc(const unsigned short* __restrict__ h2b,
    const unsigned short* __restrict__ w1r, const float* __restrict__ b1g,
    const float* __restrict__ w2g, const float* __restrict__ b2g,
    const int* __restrict__ counts, const int* __restrict__ order,
    const float* __restrict__ ew, float* __restrict__ outp) {
  const int bid = blockIdx.x;
  const int t = threadIdx.x;
  __shared__ float ax[4][4];
  if (bid == 0) {                            // aux loss (verbatim arithmetic, t<256)
    if (t < 256) {
      const float* pr = outp + 40960;        // probs_out
      float s0 = 0.f, s1 = 0.f, s2 = 0.f, s3 = 0.f;
      for (int i = t; i < 4096; i += 256) {
        const float4 v = *(const float4*)(pr + (size_t)i * 4);
        s0 += v.x; s1 += v.y; s2 += v.z; s3 += v.w;
      }
#pragma unroll
      for (int k = 1; k < 64; k <<= 1) {
        s0 += __shfl_xor(s0, k); s1 += __shfl_xor(s1, k);
        s2 += __shfl_xor(s2, k); s3 += __shfl_xor(s3, k);
      }
      if ((t & 63) == 0) {
        const int w = t >> 6;
        ax[w][0] = s0; ax[w][1] = s1; ax[w][2] = s2; ax[w][3] = s3;
      }
    }
    __syncthreads();
    if (t == 0) {
      float a = 0.f;
#pragma unroll
      for (int j = 0; j < 4; ++j) {
        const float mp = (ax[0][j] + ax[1][j] + ax[2][j] + ax[3][j]) * (1.f / 4096.f) - 0.25f;
        a += mp * mp;
      }
      outp[57344] = a * 0.25f;
    }
  }
  const int e = bid >> 8, tile = bid & 255;
  const int n = counts[e];
  const int base = tile * 16;
  if (base >= n) return;
  __shared__ int sb[16];
  __shared__ float wgt[16];
  __shared__ __align__(16) unsigned short As[16][280];   // 16 x 256 k, stride 280 (bank-clean)
  __shared__ float f1s[16 * 132];
  if (t < 16) {
    const int idx = base + t;
    const int s = order[e * B_N + ((idx < n) ? idx : base)];
    sb[t] = s; wgt[t] = ew[s];
  }
  __syncthreads();
  const int lane = t & 63, wv = t >> 6;      // wv in [0,8)
  const int n16 = lane & 15, q = lane >> 4;
  const int oc = wv * 16 + n16;              // 8 waves x 16 oc = 128
  const unsigned short* wb = w1r + ((size_t)(e * 128 + oc)) * 4096 + q * 8;
  f32x4 acc = {0.f, 0.f, 0.f, 0.f};
  const int ldrow = t >> 5, ldseg = t & 31;  // 16 rows x 32 segs x 8 u16
  const unsigned short* asrc = h2b + (size_t)sb[ldrow] * 4096;
  uint4 r0 = *(const uint4*)(asrc + ldseg * 8);            // prefetch kc=0
  for (int kc = 0; kc < 4096; kc += 256) {
    *(uint4*)&As[ldrow][ldseg * 8] = r0;
    __syncthreads();
    if (kc + 256 < 4096) {                                 // prefetch next chunk (overlaps MFMA)
      r0 = *(const uint4*)(asrc + (kc + 256) + ldseg * 8);
    }
#pragma unroll
    for (int ks = 0; ks < 8; ++ks) {
      const short8 af = *(const short8*)&As[n16][ks * 32 + q * 8];   // A[m=n16][k]
      const short8 bf = *(const short8*)(wb + kc + ks * 32);         // B[k][n=oc]
      acc = __builtin_amdgcn_mfma_f32_16x16x32_bf16(af, bf, acc, 0, 0, 0);
    }
    __syncthreads();
  }
  // C layout: row m = q*4+r (sample), col = n16 (oc)
  const float bb = b1g[e * 128 + oc];
#pragma unroll
  for (int r = 0; r < 4; ++r) {
    const int m = q * 4 + r;
    f1s[m * 132 + oc] = fmaxf(acc[r] + bb, 0.f);
  }
  __syncthreads();
  int m = n - base; if (m > 16) m = 16;
  if (t < 160) {
    const int r = t / 10, o = t - r * 10;
    if (r < m) {
      const float* w2 = w2g + (e * 10 + o) * 128;
      float s = b2g[e * 10 + o];
#pragma unroll 8
      for (int c = 0; c < 128; ++c) s += f1s[r * 132 + c] * w2[c];
      outp[(size_t)sb[r] * 10 + o] = s * wgt[r];
    }
  }
}

extern "C" void kernel_launch(void* const* d_in, const int* in_sizes, int n_in,
                              void* d_out, int out_size, void* d_ws, size_t ws_size,
                              hipStream_t stream) {
  const float* x        = (const float*)d_in[0];
  const float* gw_conv  = (const float*)d_in[1];
  const float* gb_conv  = (const float*)d_in[2];
  const float* gw_fc    = (const float*)d_in[3];
  const float* gb_fc    = (const float*)d_in[4];
  const float* ew_conv1 = (const float*)d_in[5];
  const float* eb_conv1 = (const float*)d_in[6];
  const float* ew_conv2 = (const float*)d_in[7];
  const float* eb_conv2 = (const float*)d_in[8];
  const float* ew_fc1   = (const float*)d_in[9];
  const float* eb_fc1   = (const float*)d_in[10];
  const float* ew_fc2   = (const float*)d_in[11];
  const float* eb_fc2   = (const float*)d_in[12];
  float* out = (float*)d_out;
  float* ws  = (float*)d_ws;

  unsigned short* h2b = (unsigned short*)(ws + H2B_OFF);
  float* ew     = ws + EW_OFF;
  int*   order  = (int*)(ws + ORDER_OFF);
  int*   counts = (int*)(ws + CNT_OFF);
  unsigned short* w2r = (unsigned short*)(ws + W2R_OFF);
  unsigned short* w1r = (unsigned short*)(ws + W1R_OFF);
  unsigned short* w1c = (unsigned short*)(ws + W1C_OFF);

  k_front<<<2352, 256, 0, stream>>>(ew_fc1, w1r, ew_conv2, w2r, ew_conv1, w1c, counts);
  k_experts_conv<<<4096, 256, 0, stream>>>(x, gw_conv, gb_conv, gw_fc, gb_fc,
                                           w1c, eb_conv1, w2r, eb_conv2, h2b,
                                           out + 40960, ew, counts, order);
  k_fc<<<1024, 512, 0, stream>>>(h2b, w1r, eb_fc1, ew_fc2, eb_fc2,
                                 counts, order, ew, out);
}